// Round 10
// baseline (24105.536 us; speedup 1.0000x reference)
//
#include <hip/hip_runtime.h>
#include <math.h>

#define DIN 128
#define HD 64
#define NEG 0.2f

__device__ __forceinline__ float sigmoidf_(float x) { return 1.f / (1.f + __expf(-x)); }
__device__ __forceinline__ float tanhf_(float x)    { return 2.f / (1.f + __expf(-2.f*x)) - 1.f; }

// ---------------- CSR build ----------------
__global__ void k_count(const int* __restrict__ dst, int E, int* __restrict__ deg) {
  int e = blockIdx.x*256 + threadIdx.x;
  if (e < E) atomicAdd(&deg[dst[e]], 1);
}

__global__ void k_scan1(const int* __restrict__ deg, int n, int* __restrict__ rowst, int* __restrict__ bsum) {
  __shared__ int s[256];
  int i = blockIdx.x*256 + threadIdx.x;
  int v = (i < n) ? deg[i] : 0;
  s[threadIdx.x] = v;
  __syncthreads();
  for (int off = 1; off < 256; off <<= 1) {
    int t = (threadIdx.x >= off) ? s[threadIdx.x - off] : 0;
    __syncthreads();
    s[threadIdx.x] += t;
    __syncthreads();
  }
  if (i < n) rowst[i] = s[threadIdx.x] - v;
  if (threadIdx.x == 255) bsum[blockIdx.x] = s[255];
}

__global__ void k_scan2(int* bsum, int nb) {
  __shared__ int s[256];
  int v = (threadIdx.x < nb) ? bsum[threadIdx.x] : 0;
  s[threadIdx.x] = v;
  __syncthreads();
  for (int off = 1; off < 256; off <<= 1) {
    int t = (threadIdx.x >= off) ? s[threadIdx.x - off] : 0;
    __syncthreads();
    s[threadIdx.x] += t;
    __syncthreads();
  }
  if (threadIdx.x < nb) bsum[threadIdx.x] = s[threadIdx.x] - v;
}

__global__ void k_scan3(int* __restrict__ rowst, const int* __restrict__ bsum, int n, int E, int* __restrict__ deg) {
  int i = blockIdx.x*256 + threadIdx.x;
  if (i < n) { rowst[i] += bsum[blockIdx.x]; deg[i] = 0; }
  if (i == 0) rowst[n] = E;
}

__global__ void k_scatter(const int* __restrict__ src, const int* __restrict__ dst, int E,
                          const int* __restrict__ rowst, int* __restrict__ fill, int* __restrict__ csr) {
  int e = blockIdx.x*256 + threadIdx.x;
  if (e < E) {
    int d = dst[e];
    int pos = rowst[d] + atomicAdd(&fill[d], 1);
    csr[pos] = src[e];
  }
}

// ---------------- GRU weight re-layout ----------------
// B[k][c], k in [0,128): k<64 -> m-row (Wi), k>=64 -> h-row (Wh).
// c = j*4 + gate; gate 0: r-sum, 1: z-sum, 2: gi_n (Wi only), 3: gh_n (Wh only)
__global__ void k_wt2(const float* __restrict__ Wi, const float* __restrict__ Wh,
                      const float* __restrict__ bi, const float* __restrict__ bh,
                      float* __restrict__ B, float* __restrict__ bc) {
  int i = blockIdx.x*256 + threadIdx.x;
  if (i < 128*256) {
    int k = i >> 8, c = i & 255;
    int j = c >> 2, g = c & 3;
    float v;
    if (g == 0)      v = (k < 64) ? Wi[k*(3*HD) + j]        : Wh[(k-64)*(3*HD) + j];
    else if (g == 1) v = (k < 64) ? Wi[k*(3*HD) + HD + j]   : Wh[(k-64)*(3*HD) + HD + j];
    else if (g == 2) v = (k < 64) ? Wi[k*(3*HD) + 2*HD + j] : 0.f;
    else             v = (k < 64) ? 0.f                     : Wh[(k-64)*(3*HD) + 2*HD + j];
    B[i] = v;
  }
  if (i < 256) {
    int j = i >> 2, g = i & 3;
    float v;
    if (g == 0)      v = bi[j] + bh[j];
    else if (g == 1) v = bi[HD + j] + bh[HD + j];
    else if (g == 2) v = bi[2*HD + j];
    else             v = bh[2*HD + j];
    bc[i] = v;
  }
}

// ---------------- input projection as register-blocked GEMM (M=32 tile) ----------------
__global__ void __launch_bounds__(256) k_proj2(const float* __restrict__ x, const float* __restrict__ Win,
                       const float* __restrict__ bin, const float* __restrict__ aatt, int n,
                       float* __restrict__ h, float* __restrict__ ssrc, float* __restrict__ sdst) {
  __shared__ float A[DIN][32];   // 16KB
  int m_base = blockIdx.x * 32;
  int tx = threadIdx.x;
  {
    int m = tx & 31;
    int kq8 = tx >> 5;           // 0..7
    int node = m_base + m;
    bool valid = node < n;
    const float4* x4 = (const float4*)(x + (size_t)node*DIN);
#pragma unroll
    for (int it = 0; it < 4; ++it) {
      int kq = kq8*4 + it;       // 0..31
      int k0 = kq*4;
      float4 v = make_float4(0.f,0.f,0.f,0.f);
      if (valid) v = x4[kq];
      A[k0+0][m] = v.x; A[k0+1][m] = v.y; A[k0+2][m] = v.z; A[k0+3][m] = v.w;
    }
  }
  __syncthreads();

  int c_idx = tx & 31;           // 2 cols each
  int m_idx = tx >> 5;           // 8 node groups of 4
  int c0 = c_idx * 2;
  int m0 = m_idx * 4;

  float acc[4][2];
#pragma unroll
  for (int a = 0; a < 4; ++a) { acc[a][0] = 0.f; acc[a][1] = 0.f; }

#pragma unroll 4
  for (int k = 0; k < DIN; ++k) {
    float2 b = *(const float2*)(Win + k*HD + c0);
    float4 a0 = *(const float4*)(&A[k][m0]);
    float av[4] = {a0.x,a0.y,a0.z,a0.w};
#pragma unroll
    for (int a = 0; a < 4; ++a) { acc[a][0] += av[a]*b.x; acc[a][1] += av[a]*b.y; }
  }

  float b0 = bin[c0], b1 = bin[c0+1];
  float a_s0 = aatt[c0],    a_s1 = aatt[c0+1];
  float a_d0 = aatt[HD+c0], a_d1 = aatt[HD+c0+1];

#pragma unroll
  for (int a = 0; a < 4; ++a) {
    int node = m_base + m0 + a;
    float v0 = fmaxf(acc[a][0] + b0, 0.f);
    float v1 = fmaxf(acc[a][1] + b1, 0.f);
    if (node < n) {
      h[(size_t)node*HD + c0]   = v0;
      h[(size_t)node*HD + c0+1] = v1;
    }
    float ps = v0*a_s0 + v1*a_s1;
    float pd = v0*a_d0 + v1*a_d1;
#pragma unroll
    for (int off = 16; off; off >>= 1) { ps += __shfl_xor(ps, off); pd += __shfl_xor(pd, off); }
    if (c_idx == 0 && node < n) { ssrc[node] = ps; sdst[node] = pd; }
  }
}

// ---------------- fused score + softmax + gather: 16 lanes per node ----------------
__global__ void __launch_bounds__(256) k_sagg(const float* __restrict__ h, const float* __restrict__ ssrc,
                       const float* __restrict__ sdst, const int* __restrict__ rowst,
                       const int* __restrict__ csr, int n, float* __restrict__ mout) {
  int g16 = threadIdx.x >> 4;
  int l16 = threadIdx.x & 15;
  int node = blockIdx.x*16 + g16;
  if (node >= n) return;
  int s0 = rowst[node], s1 = rowst[node+1];
  int deg = s1 - s0;
  float4 acc = make_float4(0.f,0.f,0.f,0.f);
  if (deg <= 0) {
    *((float4*)(mout + (size_t)node*HD) + l16) = acc;
    return;
  }
  float sdv = sdst[node];

  if (deg <= 64) {
    float areg[4];
    int   ureg[4];
    float mx = -INFINITY;
#pragma unroll
    for (int c = 0; c < 4; ++c) {
      int idx = s0 + c*16 + l16;
      int uu = csr[(idx < s1) ? idx : s0];    // clamped safe read
      ureg[c] = uu;
      float sc = -INFINITY;
      if (idx < s1) {
        sc = ssrc[uu] + sdv;
        sc = (sc > 0.f) ? sc : NEG*sc;
      }
      areg[c] = sc;
      mx = fmaxf(mx, sc);
    }
#pragma unroll
    for (int off = 8; off; off >>= 1) mx = fmaxf(mx, __shfl_xor(mx, off, 16));
    float zs = 0.f;
#pragma unroll
    for (int c = 0; c < 4; ++c) {
      float e = __expf(areg[c] - mx);          // exp(-inf - mx) = 0 for invalid slots
      areg[c] = e;
      zs += e;
    }
#pragma unroll
    for (int off = 8; off; off >>= 1) zs += __shfl_xor(zs, off, 16);
    float zi = 1.f / (zs + 1e-16f);

#pragma unroll
    for (int c = 0; c < 4; ++c) {
      int base = s0 + c*16;
      if (base < s1) {
        int cnt = s1 - base;                  // >=1; loop caps at 16
#pragma unroll
        for (int e = 0; e < 16; ++e) {
          if (e < cnt) {
            int   ue = __shfl(ureg[c], e, 16);
            float ae = __shfl(areg[c], e, 16);
            float4 hv = *((const float4*)(h + (size_t)ue*HD) + l16);
            acc.x += ae*hv.x; acc.y += ae*hv.y; acc.z += ae*hv.z; acc.w += ae*hv.w;
          }
        }
      }
    }
    acc.x *= zi; acc.y *= zi; acc.z *= zi; acc.w *= zi;
  } else {
    float mx = -INFINITY;
    for (int i = s0 + l16; i < s1; i += 16) {
      float sc = ssrc[csr[i]] + sdv;
      sc = (sc > 0.f) ? sc : NEG*sc;
      mx = fmaxf(mx, sc);
    }
#pragma unroll
    for (int off = 8; off; off >>= 1) mx = fmaxf(mx, __shfl_xor(mx, off, 16));
    float zs = 0.f;
    for (int i = s0 + l16; i < s1; i += 16) {
      float sc = ssrc[csr[i]] + sdv;
      sc = (sc > 0.f) ? sc : NEG*sc;
      zs += __expf(sc - mx);
    }
#pragma unroll
    for (int off = 8; off; off >>= 1) zs += __shfl_xor(zs, off, 16);
    float zi = 1.f / (zs + 1e-16f);
    for (int i = s0; i < s1; ++i) {
      int u = csr[i];
      float sc = ssrc[u] + sdv;
      sc = (sc > 0.f) ? sc : NEG*sc;
      float p = __expf(sc - mx);
      float4 hv = *((const float4*)(h + (size_t)u*HD) + l16);
      acc.x += p*hv.x; acc.y += p*hv.y; acc.z += p*hv.z; acc.w += p*hv.w;
    }
    acc.x *= zi; acc.y *= zi; acc.z *= zi; acc.w *= zi;
  }
  *((float4*)(mout + (size_t)node*HD) + l16) = acc;
}

// ---------------- GRU GEMM v8: B-slice in REGISTERS, column-split across waves ----------------
// Wave w, lane l owns column c = 64w + l (j = 16w + l>>2, gate = l&3).
// breg[128] = that column of B (128 VGPR), loaded once (coalesced 256B/row/wave).
// Main loop: pure LDS-broadcast + v_fmac, zero VMEM. acc[32 nodes].
// A padded to [128][36] so h_old reads A[64+j][m] are ~2-way bank aliased (free).
__global__ void __launch_bounds__(256, 2) k_gru8(const float* __restrict__ mm, float* __restrict__ h,
                      const float* __restrict__ B, const float* __restrict__ bc,
                      const float* __restrict__ aatt, int n,
                      float* __restrict__ ssrc, float* __restrict__ sdst) {
  __shared__ float A[128][36];    // 18.4KB: rows 0..63 = m, rows 64..127 = h_old
  __shared__ float Hn[32][68];    // 8.7KB: h_new staging for phase 2
  int tx = threadIdx.x;
  int w = tx >> 6, l = tx & 63;
  int m_base = blockIdx.x * 32;

  // ---- B column into registers (issued before A staging completes; latency amortized)
  float breg[128];
  {
    const float* Bcol = B + (w*64 + l);
#pragma unroll
    for (int k = 0; k < 128; ++k) breg[k] = Bcol[(size_t)k*256];
  }

  // ---- stage A (transposed): 8 k-quad groups x 4 iterations
  {
    int m = tx & 31;
    int kq8 = tx >> 5;           // 0..7
    int node = m_base + m;
    bool valid = node < n;
    const float4* m4 = (const float4*)(mm + (size_t)node*HD);
    const float4* h4 = (const float4*)(h  + (size_t)node*HD);
#pragma unroll
    for (int it = 0; it < 4; ++it) {
      int kq = kq8*4 + it;       // 0..31
      int k0 = kq*4;
      float4 v = make_float4(0.f,0.f,0.f,0.f);
      if (valid) v = (kq < 16) ? m4[kq] : h4[kq - 16];
      A[k0+0][m] = v.x; A[k0+1][m] = v.y; A[k0+2][m] = v.z; A[k0+3][m] = v.w;
    }
  }
  __syncthreads();

  float acc[32];
#pragma unroll
  for (int m = 0; m < 32; ++m) acc[m] = 0.f;

  // ---- main loop: fully unrolled, LDS broadcast A + register B
#pragma unroll
  for (int k = 0; k < 128; ++k) {
    float b = breg[k];
#pragma unroll
    for (int mq = 0; mq < 8; ++mq) {
      float4 a = *(const float4*)(&A[k][mq*4]);
      acc[mq*4+0] = fmaf(a.x, b, acc[mq*4+0]);
      acc[mq*4+1] = fmaf(a.y, b, acc[mq*4+1]);
      acc[mq*4+2] = fmaf(a.z, b, acc[mq*4+2]);
      acc[mq*4+3] = fmaf(a.w, b, acc[mq*4+3]);
    }
  }

  // ---- phase 1: gate recombination (4-lane shuffle) + GRU pointwise
  int j = w*16 + (l >> 2);
  int gate = l & 3;
  int base = l & ~3;
  float bcv = bc[w*64 + l];
#pragma unroll
  for (int m = 0; m < 32; ++m) {
    float pre = acc[m] + bcv;
    float g0 = __shfl(pre, base + 0);
    float g1 = __shfl(pre, base + 1);
    float g2 = __shfl(pre, base + 2);
    float g3 = __shfl(pre, base + 3);
    float rg = sigmoidf_(g0);
    float zg = sigmoidf_(g1);
    float ng = tanhf_(g2 + rg*g3);
    float hold = A[64 + j][m];
    float hnew = (1.f - zg)*ng + zg*hold;
    if (gate == 0) Hn[m][j] = hnew;
  }
  __syncthreads();

  // ---- phase 2: coalesced h write + ssrc/sdst reduction
  {
    int node2 = tx >> 3;         // 0..31
    int jb = (tx & 7) * 8;       // 0..56
    float4 h0 = *(const float4*)(&Hn[node2][jb]);
    float4 h1 = *(const float4*)(&Hn[node2][jb+4]);
    int gnode = m_base + node2;
    if (gnode < n) {
      *(float4*)(h + (size_t)gnode*HD + jb)     = h0;
      *(float4*)(h + (size_t)gnode*HD + jb + 4) = h1;
    }
    float4 as0 = *(const float4*)(aatt + jb);
    float4 as1 = *(const float4*)(aatt + jb + 4);
    float4 ad0 = *(const float4*)(aatt + HD + jb);
    float4 ad1 = *(const float4*)(aatt + HD + jb + 4);
    float ps = h0.x*as0.x + h0.y*as0.y + h0.z*as0.z + h0.w*as0.w
             + h1.x*as1.x + h1.y*as1.y + h1.z*as1.z + h1.w*as1.w;
    float pd = h0.x*ad0.x + h0.y*ad0.y + h0.z*ad0.z + h0.w*ad0.w
             + h1.x*ad1.x + h1.y*ad1.y + h1.z*ad1.z + h1.w*ad1.w;
#pragma unroll
    for (int off = 4; off; off >>= 1) { ps += __shfl_xor(ps, off, 8); pd += __shfl_xor(pd, off, 8); }
    if ((tx & 7) == 0 && gnode < n) { ssrc[gnode] = ps; sdst[gnode] = pd; }
  }
}

// ---------------- pooling: two-stage ----------------
__device__ __forceinline__ int lower_bound_i(const int* a, int n, int key) {
  int lo = 0, hi = n;
  while (lo < hi) { int mid = (lo + hi) >> 1; if (a[mid] < key) lo = mid + 1; else hi = mid; }
  return lo;
}

__global__ void k_pool1(const float* __restrict__ h, const int* __restrict__ batch, int n,
                        float* __restrict__ psum, float* __restrict__ pmax) {
  int g = blockIdx.x >> 3, slice = blockIdx.x & 7;
  int lane = threadIdx.x;            // 64 lanes = HD
  int lo = lower_bound_i(batch, n, g);
  int hi = lower_bound_i(batch, n, g + 1);
  int span = hi - lo;
  int s0 = lo + (int)(((long long)span * slice) >> 3);
  int s1 = lo + (int)(((long long)span * (slice + 1)) >> 3);
  float sum0 = 0.f, sum1 = 0.f, sum2 = 0.f, sum3 = 0.f;
  float mx0 = -INFINITY, mx1 = -INFINITY, mx2 = -INFINITY, mx3 = -INFINITY;
  int i = s0;
  for (; i + 3 < s1; i += 4) {
    float v0 = h[(size_t)(i+0)*HD + lane];
    float v1 = h[(size_t)(i+1)*HD + lane];
    float v2 = h[(size_t)(i+2)*HD + lane];
    float v3 = h[(size_t)(i+3)*HD + lane];
    sum0 += v0; sum1 += v1; sum2 += v2; sum3 += v3;
    mx0 = fmaxf(mx0, v0); mx1 = fmaxf(mx1, v1); mx2 = fmaxf(mx2, v2); mx3 = fmaxf(mx3, v3);
  }
  for (; i < s1; ++i) {
    float v = h[(size_t)i*HD + lane];
    sum0 += v; mx0 = fmaxf(mx0, v);
  }
  float sum = (sum0 + sum1) + (sum2 + sum3);
  float mx = fmaxf(fmaxf(mx0, mx1), fmaxf(mx2, mx3));
  psum[(size_t)blockIdx.x*HD + lane] = sum;
  pmax[(size_t)blockIdx.x*HD + lane] = mx;
}

__global__ void k_pool2(const float* __restrict__ psum, const float* __restrict__ pmax,
                        const int* __restrict__ batch, int n, float* __restrict__ gpool) {
  int g = blockIdx.x;
  int lane = threadIdx.x;
  int lo = lower_bound_i(batch, n, g);
  int hi = lower_bound_i(batch, n, g + 1);
  int cnt = hi - lo;
  float sum = 0.f, mx = -INFINITY;
#pragma unroll
  for (int s = 0; s < 8; ++s) {
    sum += psum[(size_t)(g*8+s)*HD + lane];
    mx = fmaxf(mx, pmax[(size_t)(g*8+s)*HD + lane]);
  }
  float mean = sum / fmaxf((float)cnt, 1.f);
  if (cnt <= 0 || !isfinite(mx)) mx = 0.f;
  gpool[(size_t)g*2*HD + lane] = mean;
  gpool[(size_t)g*2*HD + HD + lane] = mx;
}

// ---------------- MLP head (block per graph, one wave) ----------------
__global__ void k_head(const float* __restrict__ gpool, const float* __restrict__ W1,
                       const float* __restrict__ b1, const float* __restrict__ W2,
                       const float* __restrict__ b2, float* __restrict__ out) {
  int g = blockIdx.x, j = threadIdx.x;
  const float* gr = gpool + (size_t)g*2*HD;
  float acc = b1[j];
#pragma unroll
  for (int k = 0; k < 2*HD; ++k) acc += gr[k] * W1[k*HD + j];
  acc = fmaxf(acc, 0.f);
  float v = acc * W2[j];
#pragma unroll
  for (int off = 32; off; off >>= 1) v += __shfl_xor(v, off);
  if (j == 0) out[g] = v + b2[0];
}

extern "C" void kernel_launch(void* const* d_in, const int* in_sizes, int n_in,
                              void* d_out, int out_size, void* d_ws, size_t ws_size,
                              hipStream_t stream) {
  const float* x     = (const float*)d_in[0];
  const int*   ei    = (const int*)d_in[1];
  const int*   batch = (const int*)d_in[2];
  const float* Win   = (const float*)d_in[3];
  const float* bin   = (const float*)d_in[4];
  const float* aatt  = (const float*)d_in[5];
  const float* Wi    = (const float*)d_in[6];
  const float* Wh    = (const float*)d_in[7];
  const float* bi    = (const float*)d_in[8];
  const float* bh    = (const float*)d_in[9];
  const float* W1    = (const float*)d_in[10];
  const float* b1    = (const float*)d_in[11];
  const float* W2    = (const float*)d_in[12];
  const float* b2    = (const float*)d_in[13];
  float* out = (float*)d_out;

  int N = in_sizes[0] / DIN;
  int E = in_sizes[1] / 2;
  int G = out_size;

  const int* srcp = ei;
  const int* dstp = ei + E;

  char* base = (char*)d_ws;
  size_t off = 0;
  auto alloc = [&](size_t bytes) -> char* {
    char* p = base + off;
    off += (bytes + 255) & ~(size_t)255;
    return p;
  };
  float* h     = (float*)alloc((size_t)N*HD*4);
  float* mbuf  = (float*)alloc((size_t)N*HD*4);
  float* ssrc  = (float*)alloc((size_t)N*4);
  float* sdst  = (float*)alloc((size_t)N*4);
  int*   deg   = (int*)  alloc((size_t)N*4);
  int*   rowst = (int*)  alloc((size_t)(N+1)*4);
  int*   csr   = (int*)  alloc((size_t)E*4);
  float* B     = (float*)alloc((size_t)128*256*4);
  float* bc    = (float*)alloc((size_t)256*4);
  float* gpool = (float*)alloc((size_t)G*2*HD*4);
  float* psum  = (float*)alloc((size_t)G*8*HD*4);
  float* pmax  = (float*)alloc((size_t)G*8*HD*4);
  int*   bsum  = (int*)  alloc(1024);
  (void)ws_size; (void)n_in;

  int nbN = (N + 255)/256, nbE = (E + 255)/256;

  hipMemsetAsync(deg, 0, (size_t)N*4, stream);
  k_count<<<nbE, 256, 0, stream>>>(dstp, E, deg);
  k_scan1<<<nbN, 256, 0, stream>>>(deg, N, rowst, bsum);
  k_scan2<<<1, 256, 0, stream>>>(bsum, nbN);
  k_scan3<<<nbN, 256, 0, stream>>>(rowst, bsum, N, E, deg);
  k_scatter<<<nbE, 256, 0, stream>>>(srcp, dstp, E, rowst, deg, csr);
  k_wt2<<<(128*256 + 255)/256, 256, 0, stream>>>(Wi, Wh, bi, bh, B, bc);
  k_proj2<<<(N + 31)/32, 256, 0, stream>>>(x, Win, bin, aatt, N, h, ssrc, sdst);
  for (int t = 0; t < 3; ++t) {
    k_sagg<<<(N + 15)/16, 256, 0, stream>>>(h, ssrc, sdst, rowst, csr, N, mbuf);
    k_gru8<<<(N + 31)/32, 256, 0, stream>>>(mbuf, h, B, bc, aatt, N, ssrc, sdst);
  }
  k_pool1<<<G*8, 64, 0, stream>>>(h, batch, N, psum, pmax);
  k_pool2<<<G, 64, 0, stream>>>(psum, pmax, batch, N, gpool);
  k_head<<<G, 64, 0, stream>>>(gpool, W1, b1, W2, b2, out);
}

// Round 11
// 393.969 us; speedup vs baseline: 61.1864x; 61.1864x over previous
//
#include <hip/hip_runtime.h>
#include <math.h>

#define DIN 128
#define HD 64
#define NEG 0.2f

typedef short s16x8 __attribute__((ext_vector_type(8)));
typedef float f32x4 __attribute__((ext_vector_type(4)));

__device__ __forceinline__ float sigmoidf_(float x) { return 1.f / (1.f + __expf(-x)); }
__device__ __forceinline__ float tanhf_(float x)    { return 2.f / (1.f + __expf(-2.f*x)) - 1.f; }

// split fp32 pair into packed bf16 (truncation; residual captured by lo)
__device__ __forceinline__ void split2(float a, float b, unsigned& dh, unsigned& dl) {
  unsigned ha = __float_as_uint(a) & 0xffff0000u;
  unsigned hb = __float_as_uint(b) & 0xffff0000u;
  float ra = a - __uint_as_float(ha);
  float rb = b - __uint_as_float(hb);
  unsigned la = __float_as_uint(ra) & 0xffff0000u;
  unsigned lb = __float_as_uint(rb) & 0xffff0000u;
  dh = (ha >> 16) | hb;
  dl = (la >> 16) | lb;
}

__device__ __forceinline__ f32x4 mfma16(uint4 a, uint4 b, f32x4 c) {
  return __builtin_amdgcn_mfma_f32_16x16x32_bf16(
      __builtin_bit_cast(s16x8, a), __builtin_bit_cast(s16x8, b), c, 0, 0, 0);
}

// ---------------- CSR build ----------------
__global__ void k_count(const int* __restrict__ dst, int E, int* __restrict__ deg) {
  int e = blockIdx.x*256 + threadIdx.x;
  if (e < E) atomicAdd(&deg[dst[e]], 1);
}

__global__ void k_scan1(const int* __restrict__ deg, int n, int* __restrict__ rowst, int* __restrict__ bsum) {
  __shared__ int s[256];
  int i = blockIdx.x*256 + threadIdx.x;
  int v = (i < n) ? deg[i] : 0;
  s[threadIdx.x] = v;
  __syncthreads();
  for (int off = 1; off < 256; off <<= 1) {
    int t = (threadIdx.x >= off) ? s[threadIdx.x - off] : 0;
    __syncthreads();
    s[threadIdx.x] += t;
    __syncthreads();
  }
  if (i < n) rowst[i] = s[threadIdx.x] - v;
  if (threadIdx.x == 255) bsum[blockIdx.x] = s[255];
}

__global__ void k_scan2(int* bsum, int nb) {
  __shared__ int s[256];
  int v = (threadIdx.x < nb) ? bsum[threadIdx.x] : 0;
  s[threadIdx.x] = v;
  __syncthreads();
  for (int off = 1; off < 256; off <<= 1) {
    int t = (threadIdx.x >= off) ? s[threadIdx.x - off] : 0;
    __syncthreads();
    s[threadIdx.x] += t;
    __syncthreads();
  }
  if (threadIdx.x < nb) bsum[threadIdx.x] = s[threadIdx.x] - v;
}

__global__ void k_scan3(int* __restrict__ rowst, const int* __restrict__ bsum, int n, int E, int* __restrict__ deg) {
  int i = blockIdx.x*256 + threadIdx.x;
  if (i < n) { rowst[i] += bsum[blockIdx.x]; deg[i] = 0; }
  if (i == 0) rowst[n] = E;
}

__global__ void k_scatter(const int* __restrict__ src, const int* __restrict__ dst, int E,
                          const int* __restrict__ rowst, int* __restrict__ fill, int* __restrict__ csr) {
  int e = blockIdx.x*256 + threadIdx.x;
  if (e < E) {
    int d = dst[e];
    int pos = rowst[d] + atomicAdd(&fill[d], 1);
    csr[pos] = src[e];
  }
}

// ---------------- GRU weight pack for MFMA fragments ----------------
// Logical B[k][c], k in [0,128): k<64 -> Wi row, k>=64 -> Wh row; c = j*4+gate.
// Fragment order: for (ks, ntg, lane, dword): elem k = 32ks + 8*(lane>>4) + 2*dword + half,
// col = 16*ntg + (lane&15). hi/lo split planes (64KB each).
__global__ void k_wtp(const float* __restrict__ Wi, const float* __restrict__ Wh,
                      const float* __restrict__ bi, const float* __restrict__ bh,
                      unsigned* __restrict__ Bhi, unsigned* __restrict__ Blo,
                      float* __restrict__ bc) {
  int idx = blockIdx.x*256 + threadIdx.x;
  if (idx < 16384) {
    int jd  = idx & 3;
    int l   = (idx >> 2) & 63;
    int ntg = (idx >> 8) & 15;
    int ks  = idx >> 12;
    int col = ntg*16 + (l & 15);
    int j = col >> 2, g = col & 3;
    unsigned dh = 0, dl = 0;
#pragma unroll
    for (int half = 0; half < 2; ++half) {
      int k = ks*32 + (l >> 4)*8 + jd*2 + half;
      float v;
      if (g == 0)      v = (k < 64) ? Wi[k*(3*HD) + j]        : Wh[(k-64)*(3*HD) + j];
      else if (g == 1) v = (k < 64) ? Wi[k*(3*HD) + HD + j]   : Wh[(k-64)*(3*HD) + HD + j];
      else if (g == 2) v = (k < 64) ? Wi[k*(3*HD) + 2*HD + j] : 0.f;
      else             v = (k < 64) ? 0.f                     : Wh[(k-64)*(3*HD) + 2*HD + j];
      unsigned hv = __float_as_uint(v) & 0xffff0000u;
      float rf = v - __uint_as_float(hv);
      unsigned lv = __float_as_uint(rf) & 0xffff0000u;
      dh |= (hv >> 16) << (16*half);
      dl |= (lv >> 16) << (16*half);
    }
    Bhi[idx] = dh;
    Blo[idx] = dl;
  }
  if (idx < 256) {
    int j = idx >> 2, g = idx & 3;
    float v;
    if (g == 0)      v = bi[j] + bh[j];
    else if (g == 1) v = bi[HD + j] + bh[HD + j];
    else if (g == 2) v = bi[2*HD + j];
    else             v = bh[2*HD + j];
    bc[idx] = v;
  }
}

// ---------------- input projection as register-blocked GEMM (M=32 tile) ----------------
__global__ void __launch_bounds__(256) k_proj2(const float* __restrict__ x, const float* __restrict__ Win,
                       const float* __restrict__ bin, const float* __restrict__ aatt, int n,
                       float* __restrict__ h, float* __restrict__ ssrc, float* __restrict__ sdst) {
  __shared__ float A[DIN][32];   // 16KB
  int m_base = blockIdx.x * 32;
  int tx = threadIdx.x;
  {
    int m = tx & 31;
    int kq8 = tx >> 5;           // 0..7
    int node = m_base + m;
    bool valid = node < n;
    const float4* x4 = (const float4*)(x + (size_t)node*DIN);
#pragma unroll
    for (int it = 0; it < 4; ++it) {
      int kq = kq8*4 + it;       // 0..31
      int k0 = kq*4;
      float4 v = make_float4(0.f,0.f,0.f,0.f);
      if (valid) v = x4[kq];
      A[k0+0][m] = v.x; A[k0+1][m] = v.y; A[k0+2][m] = v.z; A[k0+3][m] = v.w;
    }
  }
  __syncthreads();

  int c_idx = tx & 31;
  int m_idx = tx >> 5;
  int c0 = c_idx * 2;
  int m0 = m_idx * 4;

  float acc[4][2];
#pragma unroll
  for (int a = 0; a < 4; ++a) { acc[a][0] = 0.f; acc[a][1] = 0.f; }

#pragma unroll 4
  for (int k = 0; k < DIN; ++k) {
    float2 b = *(const float2*)(Win + k*HD + c0);
    float4 a0 = *(const float4*)(&A[k][m0]);
    float av[4] = {a0.x,a0.y,a0.z,a0.w};
#pragma unroll
    for (int a = 0; a < 4; ++a) { acc[a][0] += av[a]*b.x; acc[a][1] += av[a]*b.y; }
  }

  float b0 = bin[c0], b1 = bin[c0+1];
  float a_s0 = aatt[c0],    a_s1 = aatt[c0+1];
  float a_d0 = aatt[HD+c0], a_d1 = aatt[HD+c0+1];

#pragma unroll
  for (int a = 0; a < 4; ++a) {
    int node = m_base + m0 + a;
    float v0 = fmaxf(acc[a][0] + b0, 0.f);
    float v1 = fmaxf(acc[a][1] + b1, 0.f);
    if (node < n) {
      h[(size_t)node*HD + c0]   = v0;
      h[(size_t)node*HD + c0+1] = v1;
    }
    float ps = v0*a_s0 + v1*a_s1;
    float pd = v0*a_d0 + v1*a_d1;
#pragma unroll
    for (int off = 16; off; off >>= 1) { ps += __shfl_xor(ps, off); pd += __shfl_xor(pd, off); }
    if (c_idx == 0 && node < n) { ssrc[node] = ps; sdst[node] = pd; }
  }
}

// ---------------- fused score + softmax + gather: 16 lanes per node ----------------
__global__ void __launch_bounds__(256) k_sagg(const float* __restrict__ h, const float* __restrict__ ssrc,
                       const float* __restrict__ sdst, const int* __restrict__ rowst,
                       const int* __restrict__ csr, int n, float* __restrict__ mout) {
  int g16 = threadIdx.x >> 4;
  int l16 = threadIdx.x & 15;
  int node = blockIdx.x*16 + g16;
  if (node >= n) return;
  int s0 = rowst[node], s1 = rowst[node+1];
  int deg = s1 - s0;
  float4 acc = make_float4(0.f,0.f,0.f,0.f);
  if (deg <= 0) {
    *((float4*)(mout + (size_t)node*HD) + l16) = acc;
    return;
  }
  float sdv = sdst[node];

  if (deg <= 64) {
    float areg[4];
    int   ureg[4];
    float mx = -INFINITY;
#pragma unroll
    for (int c = 0; c < 4; ++c) {
      int idx = s0 + c*16 + l16;
      int uu = csr[(idx < s1) ? idx : s0];
      ureg[c] = uu;
      float sc = -INFINITY;
      if (idx < s1) {
        sc = ssrc[uu] + sdv;
        sc = (sc > 0.f) ? sc : NEG*sc;
      }
      areg[c] = sc;
      mx = fmaxf(mx, sc);
    }
#pragma unroll
    for (int off = 8; off; off >>= 1) mx = fmaxf(mx, __shfl_xor(mx, off, 16));
    float zs = 0.f;
#pragma unroll
    for (int c = 0; c < 4; ++c) {
      float e = __expf(areg[c] - mx);
      areg[c] = e;
      zs += e;
    }
#pragma unroll
    for (int off = 8; off; off >>= 1) zs += __shfl_xor(zs, off, 16);
    float zi = 1.f / (zs + 1e-16f);

#pragma unroll
    for (int c = 0; c < 4; ++c) {
      int base = s0 + c*16;
      if (base < s1) {
        int cnt = s1 - base;
#pragma unroll
        for (int e = 0; e < 16; ++e) {
          if (e < cnt) {
            int   ue = __shfl(ureg[c], e, 16);
            float ae = __shfl(areg[c], e, 16);
            float4 hv = *((const float4*)(h + (size_t)ue*HD) + l16);
            acc.x += ae*hv.x; acc.y += ae*hv.y; acc.z += ae*hv.z; acc.w += ae*hv.w;
          }
        }
      }
    }
    acc.x *= zi; acc.y *= zi; acc.z *= zi; acc.w *= zi;
  } else {
    float mx = -INFINITY;
    for (int i = s0 + l16; i < s1; i += 16) {
      float sc = ssrc[csr[i]] + sdv;
      sc = (sc > 0.f) ? sc : NEG*sc;
      mx = fmaxf(mx, sc);
    }
#pragma unroll
    for (int off = 8; off; off >>= 1) mx = fmaxf(mx, __shfl_xor(mx, off, 16));
    float zs = 0.f;
    for (int i = s0 + l16; i < s1; i += 16) {
      float sc = ssrc[csr[i]] + sdv;
      sc = (sc > 0.f) ? sc : NEG*sc;
      zs += __expf(sc - mx);
    }
#pragma unroll
    for (int off = 8; off; off >>= 1) zs += __shfl_xor(zs, off, 16);
    float zi = 1.f / (zs + 1e-16f);
    for (int i = s0; i < s1; ++i) {
      int u = csr[i];
      float sc = ssrc[u] + sdv;
      sc = (sc > 0.f) ? sc : NEG*sc;
      float p = __expf(sc - mx);
      float4 hv = *((const float4*)(h + (size_t)u*HD) + l16);
      acc.x += p*hv.x; acc.y += p*hv.y; acc.z += p*hv.z; acc.w += p*hv.w;
    }
    acc.x *= zi; acc.y *= zi; acc.z *= zi; acc.w *= zi;
  }
  *((float4*)(mout + (size_t)node*HD) + l16) = acc;
}

// ---------------- GRU GEMM v9: split-bf16 MFMA (fp32 emulation, 3 products) ----------------
// M=32/block, 4 waves; wave w owns cols 64w..64w+63 (4 n-tiles), 2 m-tiles of 16.
// A fragments from global mbuf/h (row = lane&15, k = 8*(lane>>4)+i), split hi/lo in-register.
// B fragments pre-packed coalesced (k_wtp). D: row=(lane>>4)*4+r, col=lane&15 (m89-verified).
__global__ void __launch_bounds__(256, 4) k_gru9(const float* __restrict__ mm, float* __restrict__ h,
                      const unsigned* __restrict__ Bhi, const unsigned* __restrict__ Blo,
                      const float* __restrict__ bc, const float* __restrict__ aatt, int n,
                      float* __restrict__ ssrc, float* __restrict__ sdst) {
  __shared__ float Hn[32][68];
  int tx = threadIdx.x;
  int w = tx >> 6, l = tx & 63;
  int m_base = blockIdx.x * 32;
  int lrow = l & 15, lk = l >> 4;

  f32x4 acc[2][4];
#pragma unroll
  for (int mt = 0; mt < 2; ++mt)
#pragma unroll
    for (int nt = 0; nt < 4; ++nt) acc[mt][nt] = (f32x4){0.f,0.f,0.f,0.f};

#pragma unroll
  for (int ks = 0; ks < 4; ++ks) {
    uint4 ahi[2], alo[2];
#pragma unroll
    for (int mt = 0; mt < 2; ++mt) {
      size_t node = (size_t)(m_base + mt*16 + lrow);
      const float* src = (ks < 2) ? (mm + node*HD + ks*32 + lk*8)
                                  : (h  + node*HD + (ks-2)*32 + lk*8);
      float4 v0 = *(const float4*)(src);
      float4 v1 = *(const float4*)(src + 4);
      split2(v0.x, v0.y, ahi[mt].x, alo[mt].x);
      split2(v0.z, v0.w, ahi[mt].y, alo[mt].y);
      split2(v1.x, v1.y, ahi[mt].z, alo[mt].z);
      split2(v1.z, v1.w, ahi[mt].w, alo[mt].w);
    }
#pragma unroll
    for (int nt = 0; nt < 4; ++nt) {
      int ntg = w*4 + nt;
      int fidx = (ks*16 + ntg)*64 + l;
      uint4 bh_ = *((const uint4*)Bhi + fidx);
      uint4 bl_ = *((const uint4*)Blo + fidx);
#pragma unroll
      for (int mt = 0; mt < 2; ++mt) {
        acc[mt][nt] = mfma16(ahi[mt], bh_, acc[mt][nt]);
        acc[mt][nt] = mfma16(ahi[mt], bl_, acc[mt][nt]);
        acc[mt][nt] = mfma16(alo[mt], bh_, acc[mt][nt]);
      }
    }
  }

  // ---- phase 1: gate recombination via 4-lane shfl + GRU pointwise -> Hn
  int jj = (l & 12) >> 2;
  int sb = (l & 48) | (l & 12);
  int gate = l & 3;
#pragma unroll
  for (int nt = 0; nt < 4; ++nt) {
    int cbase = w*64 + nt*16 + (l & 12);
    float4 bc4 = *(const float4*)(bc + cbase);
    int j = w*16 + nt*4 + jj;
#pragma unroll
    for (int mt = 0; mt < 2; ++mt) {
      f32x4 a4 = acc[mt][nt];
#pragma unroll
      for (int r = 0; r < 4; ++r) {
        float pre = a4[r];
        float g0 = __shfl(pre, sb + 0);
        float g1 = __shfl(pre, sb + 1);
        float g2 = __shfl(pre, sb + 2);
        float g3 = __shfl(pre, sb + 3);
        float rg = sigmoidf_(g0 + bc4.x);
        float zg = sigmoidf_(g1 + bc4.y);
        float ng = tanhf_(g2 + bc4.z + rg*(g3 + bc4.w));
        int noder = m_base + mt*16 + lk*4 + r;
        if (gate == r && noder < n) {
          float hold = h[(size_t)noder*HD + j];
          Hn[mt*16 + lk*4 + r][j] = (1.f - zg)*ng + zg*hold;
        }
      }
    }
  }
  __syncthreads();

  // ---- phase 2: coalesced h write + ssrc/sdst reduction
  {
    int node2 = tx >> 3;
    int jb = (tx & 7) * 8;
    float4 h0 = *(const float4*)(&Hn[node2][jb]);
    float4 h1 = *(const float4*)(&Hn[node2][jb+4]);
    int gnode = m_base + node2;
    if (gnode < n) {
      *(float4*)(h + (size_t)gnode*HD + jb)     = h0;
      *(float4*)(h + (size_t)gnode*HD + jb + 4) = h1;
    }
    float4 as0 = *(const float4*)(aatt + jb);
    float4 as1 = *(const float4*)(aatt + jb + 4);
    float4 ad0 = *(const float4*)(aatt + HD + jb);
    float4 ad1 = *(const float4*)(aatt + HD + jb + 4);
    float ps = h0.x*as0.x + h0.y*as0.y + h0.z*as0.z + h0.w*as0.w
             + h1.x*as1.x + h1.y*as1.y + h1.z*as1.z + h1.w*as1.w;
    float pd = h0.x*ad0.x + h0.y*ad0.y + h0.z*ad0.z + h0.w*ad0.w
             + h1.x*ad1.x + h1.y*ad1.y + h1.z*ad1.z + h1.w*ad1.w;
#pragma unroll
    for (int off = 4; off; off >>= 1) { ps += __shfl_xor(ps, off, 8); pd += __shfl_xor(pd, off, 8); }
    if ((tx & 7) == 0 && gnode < n) { ssrc[gnode] = ps; sdst[gnode] = pd; }
  }
}

// ---------------- pooling: two-stage ----------------
__device__ __forceinline__ int lower_bound_i(const int* a, int n, int key) {
  int lo = 0, hi = n;
  while (lo < hi) { int mid = (lo + hi) >> 1; if (a[mid] < key) lo = mid + 1; else hi = mid; }
  return lo;
}

__global__ void k_pool1(const float* __restrict__ h, const int* __restrict__ batch, int n,
                        float* __restrict__ psum, float* __restrict__ pmax) {
  int g = blockIdx.x >> 3, slice = blockIdx.x & 7;
  int lane = threadIdx.x;
  int lo = lower_bound_i(batch, n, g);
  int hi = lower_bound_i(batch, n, g + 1);
  int span = hi - lo;
  int s0 = lo + (int)(((long long)span * slice) >> 3);
  int s1 = lo + (int)(((long long)span * (slice + 1)) >> 3);
  float sum0 = 0.f, sum1 = 0.f, sum2 = 0.f, sum3 = 0.f;
  float mx0 = -INFINITY, mx1 = -INFINITY, mx2 = -INFINITY, mx3 = -INFINITY;
  int i = s0;
  for (; i + 3 < s1; i += 4) {
    float v0 = h[(size_t)(i+0)*HD + lane];
    float v1 = h[(size_t)(i+1)*HD + lane];
    float v2 = h[(size_t)(i+2)*HD + lane];
    float v3 = h[(size_t)(i+3)*HD + lane];
    sum0 += v0; sum1 += v1; sum2 += v2; sum3 += v3;
    mx0 = fmaxf(mx0, v0); mx1 = fmaxf(mx1, v1); mx2 = fmaxf(mx2, v2); mx3 = fmaxf(mx3, v3);
  }
  for (; i < s1; ++i) {
    float v = h[(size_t)i*HD + lane];
    sum0 += v; mx0 = fmaxf(mx0, v);
  }
  float sum = (sum0 + sum1) + (sum2 + sum3);
  float mx = fmaxf(fmaxf(mx0, mx1), fmaxf(mx2, mx3));
  psum[(size_t)blockIdx.x*HD + lane] = sum;
  pmax[(size_t)blockIdx.x*HD + lane] = mx;
}

__global__ void k_pool2(const float* __restrict__ psum, const float* __restrict__ pmax,
                        const int* __restrict__ batch, int n, float* __restrict__ gpool) {
  int g = blockIdx.x;
  int lane = threadIdx.x;
  int lo = lower_bound_i(batch, n, g);
  int hi = lower_bound_i(batch, n, g + 1);
  int cnt = hi - lo;
  float sum = 0.f, mx = -INFINITY;
#pragma unroll
  for (int s = 0; s < 8; ++s) {
    sum += psum[(size_t)(g*8+s)*HD + lane];
    mx = fmaxf(mx, pmax[(size_t)(g*8+s)*HD + lane]);
  }
  float mean = sum / fmaxf((float)cnt, 1.f);
  if (cnt <= 0 || !isfinite(mx)) mx = 0.f;
  gpool[(size_t)g*2*HD + lane] = mean;
  gpool[(size_t)g*2*HD + HD + lane] = mx;
}

// ---------------- MLP head (block per graph, one wave) ----------------
__global__ void k_head(const float* __restrict__ gpool, const float* __restrict__ W1,
                       const float* __restrict__ b1, const float* __restrict__ W2,
                       const float* __restrict__ b2, float* __restrict__ out) {
  int g = blockIdx.x, j = threadIdx.x;
  const float* gr = gpool + (size_t)g*2*HD;
  float acc = b1[j];
#pragma unroll
  for (int k = 0; k < 2*HD; ++k) acc += gr[k] * W1[k*HD + j];
  acc = fmaxf(acc, 0.f);
  float v = acc * W2[j];
#pragma unroll
  for (int off = 32; off; off >>= 1) v += __shfl_xor(v, off);
  if (j == 0) out[g] = v + b2[0];
}

extern "C" void kernel_launch(void* const* d_in, const int* in_sizes, int n_in,
                              void* d_out, int out_size, void* d_ws, size_t ws_size,
                              hipStream_t stream) {
  const float* x     = (const float*)d_in[0];
  const int*   ei    = (const int*)d_in[1];
  const int*   batch = (const int*)d_in[2];
  const float* Win   = (const float*)d_in[3];
  const float* bin   = (const float*)d_in[4];
  const float* aatt  = (const float*)d_in[5];
  const float* Wi    = (const float*)d_in[6];
  const float* Wh    = (const float*)d_in[7];
  const float* bi    = (const float*)d_in[8];
  const float* bh    = (const float*)d_in[9];
  const float* W1    = (const float*)d_in[10];
  const float* b1    = (const float*)d_in[11];
  const float* W2    = (const float*)d_in[12];
  const float* b2    = (const float*)d_in[13];
  float* out = (float*)d_out;

  int N = in_sizes[0] / DIN;
  int E = in_sizes[1] / 2;
  int G = out_size;

  const int* srcp = ei;
  const int* dstp = ei + E;

  char* base = (char*)d_ws;
  size_t off = 0;
  auto alloc = [&](size_t bytes) -> char* {
    char* p = base + off;
    off += (bytes + 255) & ~(size_t)255;
    return p;
  };
  float* h     = (float*)alloc((size_t)N*HD*4);
  float* mbuf  = (float*)alloc((size_t)N*HD*4);
  float* ssrc  = (float*)alloc((size_t)N*4);
  float* sdst  = (float*)alloc((size_t)N*4);
  int*   deg   = (int*)  alloc((size_t)N*4);
  int*   rowst = (int*)  alloc((size_t)(N+1)*4);
  int*   csr   = (int*)  alloc((size_t)E*4);
  unsigned* Bhi = (unsigned*)alloc((size_t)16384*4);
  unsigned* Blo = (unsigned*)alloc((size_t)16384*4);
  float* bc    = (float*)alloc((size_t)256*4);
  float* gpool = (float*)alloc((size_t)G*2*HD*4);
  float* psum  = (float*)alloc((size_t)G*8*HD*4);
  float* pmax  = (float*)alloc((size_t)G*8*HD*4);
  int*   bsum  = (int*)  alloc(1024);
  (void)ws_size; (void)n_in;

  int nbN = (N + 255)/256, nbE = (E + 255)/256;

  hipMemsetAsync(deg, 0, (size_t)N*4, stream);
  k_count<<<nbE, 256, 0, stream>>>(dstp, E, deg);
  k_scan1<<<nbN, 256, 0, stream>>>(deg, N, rowst, bsum);
  k_scan2<<<1, 256, 0, stream>>>(bsum, nbN);
  k_scan3<<<nbN, 256, 0, stream>>>(rowst, bsum, N, E, deg);
  k_scatter<<<nbE, 256, 0, stream>>>(srcp, dstp, E, rowst, deg, csr);
  k_wtp<<<64, 256, 0, stream>>>(Wi, Wh, bi, bh, Bhi, Blo, bc);
  k_proj2<<<(N + 31)/32, 256, 0, stream>>>(x, Win, bin, aatt, N, h, ssrc, sdst);
  for (int t = 0; t < 3; ++t) {
    k_sagg<<<(N + 15)/16, 256, 0, stream>>>(h, ssrc, sdst, rowst, csr, N, mbuf);
    k_gru9<<<(N + 31)/32, 256, 0, stream>>>(mbuf, h, Bhi, Blo, bc, aatt, N, ssrc, sdst);
  }
  k_pool1<<<G*8, 64, 0, stream>>>(h, batch, N, psum, pmax);
  k_pool2<<<G, 64, 0, stream>>>(psum, pmax, batch, N, gpool);
  k_head<<<G, 64, 0, stream>>>(gpool, W1, b1, W2, b2, out);
}

// Round 12
// 343.245 us; speedup vs baseline: 70.2284x; 1.1478x over previous
//
#include <hip/hip_runtime.h>
#include <math.h>

#define DIN 128
#define HD 64
#define NEG 0.2f

typedef short s16x8 __attribute__((ext_vector_type(8)));
typedef float f32x4 __attribute__((ext_vector_type(4)));

__device__ __forceinline__ float sigmoidf_(float x) { return 1.f / (1.f + __expf(-x)); }
__device__ __forceinline__ float tanhf_(float x)    { return 2.f / (1.f + __expf(-2.f*x)) - 1.f; }

// split fp32 pair into packed bf16 (truncation; residual captured by lo)
__device__ __forceinline__ void split2(float a, float b, unsigned& dh, unsigned& dl) {
  unsigned ha = __float_as_uint(a) & 0xffff0000u;
  unsigned hb = __float_as_uint(b) & 0xffff0000u;
  float ra = a - __uint_as_float(ha);
  float rb = b - __uint_as_float(hb);
  unsigned la = __float_as_uint(ra) & 0xffff0000u;
  unsigned lb = __float_as_uint(rb) & 0xffff0000u;
  dh = (ha >> 16) | hb;
  dl = (la >> 16) | lb;
}

__device__ __forceinline__ f32x4 mfma16(uint4 a, uint4 b, f32x4 c) {
  return __builtin_amdgcn_mfma_f32_16x16x32_bf16(
      __builtin_bit_cast(s16x8, a), __builtin_bit_cast(s16x8, b), c, 0, 0, 0);
}

// ---------------- CSR build ----------------
__global__ void k_count(const int* __restrict__ dst, int E, int* __restrict__ deg) {
  int e = blockIdx.x*256 + threadIdx.x;
  if (e < E) atomicAdd(&deg[dst[e]], 1);
}

__global__ void k_scan1(const int* __restrict__ deg, int n, int* __restrict__ rowst, int* __restrict__ bsum) {
  __shared__ int s[256];
  int i = blockIdx.x*256 + threadIdx.x;
  int v = (i < n) ? deg[i] : 0;
  s[threadIdx.x] = v;
  __syncthreads();
  for (int off = 1; off < 256; off <<= 1) {
    int t = (threadIdx.x >= off) ? s[threadIdx.x - off] : 0;
    __syncthreads();
    s[threadIdx.x] += t;
    __syncthreads();
  }
  if (i < n) rowst[i] = s[threadIdx.x] - v;
  if (threadIdx.x == 255) bsum[blockIdx.x] = s[255];
}

__global__ void k_scan2(int* bsum, int nb) {
  __shared__ int s[256];
  int v = (threadIdx.x < nb) ? bsum[threadIdx.x] : 0;
  s[threadIdx.x] = v;
  __syncthreads();
  for (int off = 1; off < 256; off <<= 1) {
    int t = (threadIdx.x >= off) ? s[threadIdx.x - off] : 0;
    __syncthreads();
    s[threadIdx.x] += t;
    __syncthreads();
  }
  if (threadIdx.x < nb) bsum[threadIdx.x] = s[threadIdx.x] - v;
}

__global__ void k_scan3(int* __restrict__ rowst, const int* __restrict__ bsum, int n, int E, int* __restrict__ deg) {
  int i = blockIdx.x*256 + threadIdx.x;
  if (i < n) { rowst[i] += bsum[blockIdx.x]; deg[i] = 0; }
  if (i == 0) rowst[n] = E;
}

__global__ void k_scatter(const int* __restrict__ src, const int* __restrict__ dst, int E,
                          const int* __restrict__ rowst, int* __restrict__ fill, int* __restrict__ csr) {
  int e = blockIdx.x*256 + threadIdx.x;
  if (e < E) {
    int d = dst[e];
    int pos = rowst[d] + atomicAdd(&fill[d], 1);
    csr[pos] = src[e];
  }
}

// ---------------- GRU weight pack for MFMA fragments (gate = nt-tile) ----------------
// Fragment (ks, ntg, lane, dword): k = 32ks + 8*(lane>>4) + 2*dword + half.
// ntg = w*4 + gate; column j = w*16 + (lane&15). So wave w's 4 n-tiles are the 4 gates
// of the SAME 16 j's -> thread-local gate recombination in the GRU kernel.
// bc2 layout: bc2[gate*64 + j].
__global__ void k_wtp(const float* __restrict__ Wi, const float* __restrict__ Wh,
                      const float* __restrict__ bi, const float* __restrict__ bh,
                      unsigned* __restrict__ Bhi, unsigned* __restrict__ Blo,
                      float* __restrict__ bc) {
  int idx = blockIdx.x*256 + threadIdx.x;
  if (idx < 16384) {
    int jd  = idx & 3;
    int l   = (idx >> 2) & 63;
    int ntg = (idx >> 8) & 15;
    int ks  = idx >> 12;
    int g = ntg & 3;
    int j = (ntg >> 2)*16 + (l & 15);
    unsigned dh = 0, dl = 0;
#pragma unroll
    for (int half = 0; half < 2; ++half) {
      int k = ks*32 + (l >> 4)*8 + jd*2 + half;
      float v;
      if (g == 0)      v = (k < 64) ? Wi[k*(3*HD) + j]        : Wh[(k-64)*(3*HD) + j];
      else if (g == 1) v = (k < 64) ? Wi[k*(3*HD) + HD + j]   : Wh[(k-64)*(3*HD) + HD + j];
      else if (g == 2) v = (k < 64) ? Wi[k*(3*HD) + 2*HD + j] : 0.f;
      else             v = (k < 64) ? 0.f                     : Wh[(k-64)*(3*HD) + 2*HD + j];
      unsigned hv = __float_as_uint(v) & 0xffff0000u;
      float rf = v - __uint_as_float(hv);
      unsigned lv = __float_as_uint(rf) & 0xffff0000u;
      dh |= (hv >> 16) << (16*half);
      dl |= (lv >> 16) << (16*half);
    }
    Bhi[idx] = dh;
    Blo[idx] = dl;
  }
  if (idx < 256) {
    int g = idx >> 6, j = idx & 63;
    float v;
    if (g == 0)      v = bi[j] + bh[j];
    else if (g == 1) v = bi[HD + j] + bh[HD + j];
    else if (g == 2) v = bi[2*HD + j];
    else             v = bh[2*HD + j];
    bc[idx] = v;
  }
}

// ---------------- input projection as register-blocked GEMM (M=32 tile) ----------------
__global__ void __launch_bounds__(256) k_proj2(const float* __restrict__ x, const float* __restrict__ Win,
                       const float* __restrict__ bin, const float* __restrict__ aatt, int n,
                       float* __restrict__ h, float* __restrict__ ssrc, float* __restrict__ sdst) {
  __shared__ float A[DIN][32];   // 16KB
  int m_base = blockIdx.x * 32;
  int tx = threadIdx.x;
  {
    int m = tx & 31;
    int kq8 = tx >> 5;           // 0..7
    int node = m_base + m;
    bool valid = node < n;
    const float4* x4 = (const float4*)(x + (size_t)node*DIN);
#pragma unroll
    for (int it = 0; it < 4; ++it) {
      int kq = kq8*4 + it;       // 0..31
      int k0 = kq*4;
      float4 v = make_float4(0.f,0.f,0.f,0.f);
      if (valid) v = x4[kq];
      A[k0+0][m] = v.x; A[k0+1][m] = v.y; A[k0+2][m] = v.z; A[k0+3][m] = v.w;
    }
  }
  __syncthreads();

  int c_idx = tx & 31;
  int m_idx = tx >> 5;
  int c0 = c_idx * 2;
  int m0 = m_idx * 4;

  float acc[4][2];
#pragma unroll
  for (int a = 0; a < 4; ++a) { acc[a][0] = 0.f; acc[a][1] = 0.f; }

#pragma unroll 4
  for (int k = 0; k < DIN; ++k) {
    float2 b = *(const float2*)(Win + k*HD + c0);
    float4 a0 = *(const float4*)(&A[k][m0]);
    float av[4] = {a0.x,a0.y,a0.z,a0.w};
#pragma unroll
    for (int a = 0; a < 4; ++a) { acc[a][0] += av[a]*b.x; acc[a][1] += av[a]*b.y; }
  }

  float b0 = bin[c0], b1 = bin[c0+1];
  float a_s0 = aatt[c0],    a_s1 = aatt[c0+1];
  float a_d0 = aatt[HD+c0], a_d1 = aatt[HD+c0+1];

#pragma unroll
  for (int a = 0; a < 4; ++a) {
    int node = m_base + m0 + a;
    float v0 = fmaxf(acc[a][0] + b0, 0.f);
    float v1 = fmaxf(acc[a][1] + b1, 0.f);
    if (node < n) {
      h[(size_t)node*HD + c0]   = v0;
      h[(size_t)node*HD + c0+1] = v1;
    }
    float ps = v0*a_s0 + v1*a_s1;
    float pd = v0*a_d0 + v1*a_d1;
#pragma unroll
    for (int off = 16; off; off >>= 1) { ps += __shfl_xor(ps, off); pd += __shfl_xor(pd, off); }
    if (c_idx == 0 && node < n) { ssrc[node] = ps; sdst[node] = pd; }
  }
}

// ---------------- fused score + softmax + gather: 16 lanes per node ----------------
__global__ void __launch_bounds__(256) k_sagg(const float* __restrict__ h, const float* __restrict__ ssrc,
                       const float* __restrict__ sdst, const int* __restrict__ rowst,
                       const int* __restrict__ csr, int n, float* __restrict__ mout) {
  int g16 = threadIdx.x >> 4;
  int l16 = threadIdx.x & 15;
  int node = blockIdx.x*16 + g16;
  if (node >= n) return;
  int s0 = rowst[node], s1 = rowst[node+1];
  int deg = s1 - s0;
  float4 acc = make_float4(0.f,0.f,0.f,0.f);
  if (deg <= 0) {
    *((float4*)(mout + (size_t)node*HD) + l16) = acc;
    return;
  }
  float sdv = sdst[node];

  if (deg <= 64) {
    float areg[4];
    int   ureg[4];
    float mx = -INFINITY;
#pragma unroll
    for (int c = 0; c < 4; ++c) {
      int idx = s0 + c*16 + l16;
      int uu = csr[(idx < s1) ? idx : s0];
      ureg[c] = uu;
      float sc = -INFINITY;
      if (idx < s1) {
        sc = ssrc[uu] + sdv;
        sc = (sc > 0.f) ? sc : NEG*sc;
      }
      areg[c] = sc;
      mx = fmaxf(mx, sc);
    }
#pragma unroll
    for (int off = 8; off; off >>= 1) mx = fmaxf(mx, __shfl_xor(mx, off, 16));
    float zs = 0.f;
#pragma unroll
    for (int c = 0; c < 4; ++c) {
      float e = __expf(areg[c] - mx);
      areg[c] = e;
      zs += e;
    }
#pragma unroll
    for (int off = 8; off; off >>= 1) zs += __shfl_xor(zs, off, 16);
    float zi = 1.f / (zs + 1e-16f);

#pragma unroll
    for (int c = 0; c < 4; ++c) {
      int base = s0 + c*16;
      if (base < s1) {
        int cnt = s1 - base;
#pragma unroll
        for (int e = 0; e < 16; ++e) {
          if (e < cnt) {
            int   ue = __shfl(ureg[c], e, 16);
            float ae = __shfl(areg[c], e, 16);
            float4 hv = *((const float4*)(h + (size_t)ue*HD) + l16);
            acc.x += ae*hv.x; acc.y += ae*hv.y; acc.z += ae*hv.z; acc.w += ae*hv.w;
          }
        }
      }
    }
    acc.x *= zi; acc.y *= zi; acc.z *= zi; acc.w *= zi;
  } else {
    float mx = -INFINITY;
    for (int i = s0 + l16; i < s1; i += 16) {
      float sc = ssrc[csr[i]] + sdv;
      sc = (sc > 0.f) ? sc : NEG*sc;
      mx = fmaxf(mx, sc);
    }
#pragma unroll
    for (int off = 8; off; off >>= 1) mx = fmaxf(mx, __shfl_xor(mx, off, 16));
    float zs = 0.f;
    for (int i = s0 + l16; i < s1; i += 16) {
      float sc = ssrc[csr[i]] + sdv;
      sc = (sc > 0.f) ? sc : NEG*sc;
      zs += __expf(sc - mx);
    }
#pragma unroll
    for (int off = 8; off; off >>= 1) zs += __shfl_xor(zs, off, 16);
    float zi = 1.f / (zs + 1e-16f);
    for (int i = s0; i < s1; ++i) {
      int u = csr[i];
      float sc = ssrc[u] + sdv;
      sc = (sc > 0.f) ? sc : NEG*sc;
      float p = __expf(sc - mx);
      float4 hv = *((const float4*)(h + (size_t)u*HD) + l16);
      acc.x += p*hv.x; acc.y += p*hv.y; acc.z += p*hv.z; acc.w += p*hv.w;
    }
    acc.x *= zi; acc.y *= zi; acc.z *= zi; acc.w *= zi;
  }
  *((float4*)(mout + (size_t)node*HD) + l16) = acc;
}

// ---------------- GRU GEMM v10: split-bf16 MFMA, gate-per-ntile -> thread-local epilogue ----------------
// M=32/block, 4 waves; wave w owns j in [16w,16w+16): nt = gate.
// acc[mt][gate][r] all live in the same thread -> zero-shuffle gate recombination.
__global__ void __launch_bounds__(256, 4) k_gru10(const float* __restrict__ mm, float* __restrict__ h,
                      const unsigned* __restrict__ Bhi, const unsigned* __restrict__ Blo,
                      const float* __restrict__ bc, const float* __restrict__ aatt, int n,
                      float* __restrict__ ssrc, float* __restrict__ sdst) {
  __shared__ float Hn[32][68];
  int tx = threadIdx.x;
  int w = tx >> 6, l = tx & 63;
  int m_base = blockIdx.x * 32;
  int lrow = l & 15, lk = l >> 4;

  f32x4 acc[2][4];
#pragma unroll
  for (int mt = 0; mt < 2; ++mt)
#pragma unroll
    for (int nt = 0; nt < 4; ++nt) acc[mt][nt] = (f32x4){0.f,0.f,0.f,0.f};

#pragma unroll
  for (int ks = 0; ks < 4; ++ks) {
    uint4 ahi[2], alo[2];
#pragma unroll
    for (int mt = 0; mt < 2; ++mt) {
      size_t node = (size_t)(m_base + mt*16 + lrow);
      const float* src = (ks < 2) ? (mm + node*HD + ks*32 + lk*8)
                                  : (h  + node*HD + (ks-2)*32 + lk*8);
      float4 v0 = *(const float4*)(src);
      float4 v1 = *(const float4*)(src + 4);
      split2(v0.x, v0.y, ahi[mt].x, alo[mt].x);
      split2(v0.z, v0.w, ahi[mt].y, alo[mt].y);
      split2(v1.x, v1.y, ahi[mt].z, alo[mt].z);
      split2(v1.z, v1.w, ahi[mt].w, alo[mt].w);
    }
#pragma unroll
    for (int nt = 0; nt < 4; ++nt) {
      int ntg = w*4 + nt;
      int fidx = (ks*16 + ntg)*64 + l;
      uint4 bh_ = *((const uint4*)Bhi + fidx);
      uint4 bl_ = *((const uint4*)Blo + fidx);
#pragma unroll
      for (int mt = 0; mt < 2; ++mt) {
        acc[mt][nt] = mfma16(ahi[mt], bh_, acc[mt][nt]);
        acc[mt][nt] = mfma16(ahi[mt], bl_, acc[mt][nt]);
        acc[mt][nt] = mfma16(alo[mt], bh_, acc[mt][nt]);
      }
    }
  }

  // ---- phase 1: THREAD-LOCAL gate recombination + GRU pointwise -> Hn
  int j = w*16 + (l & 15);
  float bcr = bc[j], bcz = bc[64 + j], bcg = bc[128 + j], bch = bc[192 + j];
#pragma unroll
  for (int mt = 0; mt < 2; ++mt) {
#pragma unroll
    for (int r = 0; r < 4; ++r) {
      int lr = mt*16 + lk*4 + r;
      int noder = m_base + lr;
      float rg = sigmoidf_(acc[mt][0][r] + bcr);
      float zg = sigmoidf_(acc[mt][1][r] + bcz);
      float ng = tanhf_(acc[mt][2][r] + bcg + rg*(acc[mt][3][r] + bch));
      float hold = (noder < n) ? h[(size_t)noder*HD + j] : 0.f;
      Hn[lr][j] = (1.f - zg)*ng + zg*hold;
    }
  }
  __syncthreads();

  // ---- phase 2: coalesced h write + ssrc/sdst reduction
  {
    int node2 = tx >> 3;
    int jb = (tx & 7) * 8;
    float4 h0 = *(const float4*)(&Hn[node2][jb]);
    float4 h1 = *(const float4*)(&Hn[node2][jb+4]);
    int gnode = m_base + node2;
    if (gnode < n) {
      *(float4*)(h + (size_t)gnode*HD + jb)     = h0;
      *(float4*)(h + (size_t)gnode*HD + jb + 4) = h1;
    }
    float4 as0 = *(const float4*)(aatt + jb);
    float4 as1 = *(const float4*)(aatt + jb + 4);
    float4 ad0 = *(const float4*)(aatt + HD + jb);
    float4 ad1 = *(const float4*)(aatt + HD + jb + 4);
    float ps = h0.x*as0.x + h0.y*as0.y + h0.z*as0.z + h0.w*as0.w
             + h1.x*as1.x + h1.y*as1.y + h1.z*as1.z + h1.w*as1.w;
    float pd = h0.x*ad0.x + h0.y*ad0.y + h0.z*ad0.z + h0.w*ad0.w
             + h1.x*ad1.x + h1.y*ad1.y + h1.z*ad1.z + h1.w*ad1.w;
#pragma unroll
    for (int off = 4; off; off >>= 1) { ps += __shfl_xor(ps, off, 8); pd += __shfl_xor(pd, off, 8); }
    if ((tx & 7) == 0 && gnode < n) { ssrc[gnode] = ps; sdst[gnode] = pd; }
  }
}

// ---------------- pooling: two-stage ----------------
__device__ __forceinline__ int lower_bound_i(const int* a, int n, int key) {
  int lo = 0, hi = n;
  while (lo < hi) { int mid = (lo + hi) >> 1; if (a[mid] < key) lo = mid + 1; else hi = mid; }
  return lo;
}

__global__ void k_pool1(const float* __restrict__ h, const int* __restrict__ batch, int n,
                        float* __restrict__ psum, float* __restrict__ pmax) {
  int g = blockIdx.x >> 3, slice = blockIdx.x & 7;
  int lane = threadIdx.x;
  int lo = lower_bound_i(batch, n, g);
  int hi = lower_bound_i(batch, n, g + 1);
  int span = hi - lo;
  int s0 = lo + (int)(((long long)span * slice) >> 3);
  int s1 = lo + (int)(((long long)span * (slice + 1)) >> 3);
  float sum0 = 0.f, sum1 = 0.f, sum2 = 0.f, sum3 = 0.f;
  float mx0 = -INFINITY, mx1 = -INFINITY, mx2 = -INFINITY, mx3 = -INFINITY;
  int i = s0;
  for (; i + 3 < s1; i += 4) {
    float v0 = h[(size_t)(i+0)*HD + lane];
    float v1 = h[(size_t)(i+1)*HD + lane];
    float v2 = h[(size_t)(i+2)*HD + lane];
    float v3 = h[(size_t)(i+3)*HD + lane];
    sum0 += v0; sum1 += v1; sum2 += v2; sum3 += v3;
    mx0 = fmaxf(mx0, v0); mx1 = fmaxf(mx1, v1); mx2 = fmaxf(mx2, v2); mx3 = fmaxf(mx3, v3);
  }
  for (; i < s1; ++i) {
    float v = h[(size_t)i*HD + lane];
    sum0 += v; mx0 = fmaxf(mx0, v);
  }
  float sum = (sum0 + sum1) + (sum2 + sum3);
  float mx = fmaxf(fmaxf(mx0, mx1), fmaxf(mx2, mx3));
  psum[(size_t)blockIdx.x*HD + lane] = sum;
  pmax[(size_t)blockIdx.x*HD + lane] = mx;
}

__global__ void k_pool2(const float* __restrict__ psum, const float* __restrict__ pmax,
                        const int* __restrict__ batch, int n, float* __restrict__ gpool) {
  int g = blockIdx.x;
  int lane = threadIdx.x;
  int lo = lower_bound_i(batch, n, g);
  int hi = lower_bound_i(batch, n, g + 1);
  int cnt = hi - lo;
  float sum = 0.f, mx = -INFINITY;
#pragma unroll
  for (int s = 0; s < 8; ++s) {
    sum += psum[(size_t)(g*8+s)*HD + lane];
    mx = fmaxf(mx, pmax[(size_t)(g*8+s)*HD + lane]);
  }
  float mean = sum / fmaxf((float)cnt, 1.f);
  if (cnt <= 0 || !isfinite(mx)) mx = 0.f;
  gpool[(size_t)g*2*HD + lane] = mean;
  gpool[(size_t)g*2*HD + HD + lane] = mx;
}

// ---------------- MLP head (block per graph, one wave) ----------------
__global__ void k_head(const float* __restrict__ gpool, const float* __restrict__ W1,
                       const float* __restrict__ b1, const float* __restrict__ W2,
                       const float* __restrict__ b2, float* __restrict__ out) {
  int g = blockIdx.x, j = threadIdx.x;
  const float* gr = gpool + (size_t)g*2*HD;
  float acc = b1[j];
#pragma unroll
  for (int k = 0; k < 2*HD; ++k) acc += gr[k] * W1[k*HD + j];
  acc = fmaxf(acc, 0.f);
  float v = acc * W2[j];
#pragma unroll
  for (int off = 32; off; off >>= 1) v += __shfl_xor(v, off);
  if (j == 0) out[g] = v + b2[0];
}

extern "C" void kernel_launch(void* const* d_in, const int* in_sizes, int n_in,
                              void* d_out, int out_size, void* d_ws, size_t ws_size,
                              hipStream_t stream) {
  const float* x     = (const float*)d_in[0];
  const int*   ei    = (const int*)d_in[1];
  const int*   batch = (const int*)d_in[2];
  const float* Win   = (const float*)d_in[3];
  const float* bin   = (const float*)d_in[4];
  const float* aatt  = (const float*)d_in[5];
  const float* Wi    = (const float*)d_in[6];
  const float* Wh    = (const float*)d_in[7];
  const float* bi    = (const float*)d_in[8];
  const float* bh    = (const float*)d_in[9];
  const float* W1    = (const float*)d_in[10];
  const float* b1    = (const float*)d_in[11];
  const float* W2    = (const float*)d_in[12];
  const float* b2    = (const float*)d_in[13];
  float* out = (float*)d_out;

  int N = in_sizes[0] / DIN;
  int E = in_sizes[1] / 2;
  int G = out_size;

  const int* srcp = ei;
  const int* dstp = ei + E;

  char* base = (char*)d_ws;
  size_t off = 0;
  auto alloc = [&](size_t bytes) -> char* {
    char* p = base + off;
    off += (bytes + 255) & ~(size_t)255;
    return p;
  };
  float* h     = (float*)alloc((size_t)N*HD*4);
  float* mbuf  = (float*)alloc((size_t)N*HD*4);
  float* ssrc  = (float*)alloc((size_t)N*4);
  float* sdst  = (float*)alloc((size_t)N*4);
  int*   deg   = (int*)  alloc((size_t)N*4);
  int*   rowst = (int*)  alloc((size_t)(N+1)*4);
  int*   csr   = (int*)  alloc((size_t)E*4);
  unsigned* Bhi = (unsigned*)alloc((size_t)16384*4);
  unsigned* Blo = (unsigned*)alloc((size_t)16384*4);
  float* bc    = (float*)alloc((size_t)256*4);
  float* gpool = (float*)alloc((size_t)G*2*HD*4);
  float* psum  = (float*)alloc((size_t)G*8*HD*4);
  float* pmax  = (float*)alloc((size_t)G*8*HD*4);
  int*   bsum  = (int*)  alloc(1024);
  (void)ws_size; (void)n_in;

  int nbN = (N + 255)/256, nbE = (E + 255)/256;

  hipMemsetAsync(deg, 0, (size_t)N*4, stream);
  k_count<<<nbE, 256, 0, stream>>>(dstp, E, deg);
  k_scan1<<<nbN, 256, 0, stream>>>(deg, N, rowst, bsum);
  k_scan2<<<1, 256, 0, stream>>>(bsum, nbN);
  k_scan3<<<nbN, 256, 0, stream>>>(rowst, bsum, N, E, deg);
  k_scatter<<<nbE, 256, 0, stream>>>(srcp, dstp, E, rowst, deg, csr);
  k_wtp<<<64, 256, 0, stream>>>(Wi, Wh, bi, bh, Bhi, Blo, bc);
  k_proj2<<<(N + 31)/32, 256, 0, stream>>>(x, Win, bin, aatt, N, h, ssrc, sdst);
  for (int t = 0; t < 3; ++t) {
    k_sagg<<<(N + 15)/16, 256, 0, stream>>>(h, ssrc, sdst, rowst, csr, N, mbuf);
    k_gru10<<<(N + 31)/32, 256, 0, stream>>>(mbuf, h, Bhi, Blo, bc, aatt, N, ssrc, sdst);
  }
  k_pool1<<<G*8, 64, 0, stream>>>(h, batch, N, psum, pmax);
  k_pool2<<<G, 64, 0, stream>>>(psum, pmax, batch, N, gpool);
  k_head<<<G, 64, 0, stream>>>(gpool, W1, b1, W2, b2, out);
}